// Round 2
// baseline (1422.563 us; speedup 1.0000x reference)
//
#include <hip/hip_runtime.h>
#include <stdint.h>

#define Bn 256
#define Tn 512
#define Hn 128
#define G4 512   // 4*H

typedef __attribute__((ext_vector_type(8))) short s16x8;
typedef __attribute__((ext_vector_type(4))) float f32x4;

__device__ __forceinline__ float b2f(unsigned short u) {
    union { unsigned int i; float f; } v; v.i = ((unsigned int)u) << 16; return v.f;
}
__device__ __forceinline__ unsigned short f2b(float f) {
    union { float f; unsigned int i; } v; v.f = f;
    unsigned int x = v.i;
    unsigned int r = (x + 0x7FFFu + ((x >> 16) & 1u)) >> 16;
    return (unsigned short)r;
}
// 8 consecutive fp32 -> bf16 fragment (two 16B loads + RNE converts)
__device__ __forceinline__ s16x8 cvt8v(const float* p) {
    f32x4 a = *(const f32x4*)p;
    f32x4 b = *(const f32x4*)(p + 4);
    s16x8 r;
    r[0] = (short)f2b(a[0]); r[1] = (short)f2b(a[1]);
    r[2] = (short)f2b(a[2]); r[3] = (short)f2b(a[3]);
    r[4] = (short)f2b(b[0]); r[5] = (short)f2b(b[1]);
    r[6] = (short)f2b(b[2]); r[7] = (short)f2b(b[3]);
    return r;
}
__device__ __forceinline__ float sigm(float x) {
    return __builtin_amdgcn_rcpf(1.f + __expf(-x));
}
__device__ __forceinline__ float tanh_f(float x) {
    return 1.f - 2.f * __builtin_amdgcn_rcpf(1.f + __expf(2.f * x));
}

// ---------------------------------------------------------------------------
// gx GEMM: gx[d][m][n] = sum_k A[m][k] * W_d[n][k]   (no bias; recur adds it)
// A: [M][LDA] fp32 (first K cols used), W: [512][K] fp32, gx: [2][M][512] bf16
// grid (128 M-chunks of 1024 rows, 8 col-blocks of 128), block 256 (4 waves)
// ---------------------------------------------------------------------------
template<int K, int LDA>
__global__ __launch_bounds__(256, 2)
void gemm_gx(const float* __restrict__ A,
             const float* __restrict__ Wf,
             const float* __restrict__ Wb,
             unsigned short* __restrict__ gx)
{
    constexpr int KC = (K + 31) / 32;   // 1 (K=24) or 8 (K=256)
    const int M = Bn * Tn;
    const int mchunk = blockIdx.x;
    const int colb   = blockIdx.y;      // 0..7
    const int dir    = colb >> 2;
    const int n0b    = (colb & 3) * 128;
    const float* W = dir ? Wb : Wf;
    unsigned short* out = gx + (size_t)dir * M * G4;

    const int tid = threadIdx.x;
    const int w = tid >> 6, l = tid & 63;
    const int q = l >> 4, i = l & 15;
    const int nw = n0b + w * 32;        // wave's 32-col range

    // B-frags: wave covers 2 N-tiles x KC K-frags (converted fp32->bf16 once)
    s16x8 wbf[2][KC];
#pragma unroll
    for (int nt = 0; nt < 2; ++nt) {
#pragma unroll
        for (int kf = 0; kf < KC; ++kf) {
            int ke = kf * 32 + q * 8;
            int n  = nw + nt * 16 + i;
            if (ke < K) wbf[nt][kf] = cvt8v(W + (size_t)n * K + ke);
            else        wbf[nt][kf] = s16x8{0,0,0,0,0,0,0,0};
        }
    }

    __shared__ float gbuf[4][16][36];   // per-wave repack buffer (pad 4)

    for (int mt = 0; mt < 64; ++mt) {
        int row0 = mchunk * 1024 + mt * 16;
        s16x8 aa[KC];
#pragma unroll
        for (int kf = 0; kf < KC; ++kf) {
            int ke = kf * 32 + q * 8;
            if (ke < K) aa[kf] = cvt8v(A + (size_t)(row0 + i) * LDA + ke);
            else        aa[kf] = s16x8{0,0,0,0,0,0,0,0};
        }
        f32x4 acc0 = f32x4{0.f,0.f,0.f,0.f};
        f32x4 acc1 = f32x4{0.f,0.f,0.f,0.f};
#pragma unroll
        for (int kf = 0; kf < KC; ++kf) {
            acc0 = __builtin_amdgcn_mfma_f32_16x16x32_bf16(aa[kf], wbf[0][kf], acc0, 0, 0, 0);
            acc1 = __builtin_amdgcn_mfma_f32_16x16x32_bf16(aa[kf], wbf[1][kf], acc1, 0, 0, 0);
        }
        // C/D: row = q*4+r, col = i  -> stage to LDS
#pragma unroll
        for (int r = 0; r < 4; ++r) {
            gbuf[w][q * 4 + r][0 * 16 + i] = acc0[r];
            gbuf[w][q * 4 + r][1 * 16 + i] = acc1[r];
        }
        __syncthreads();
        // coalesced bf16 store: lane -> (m = l>>2, 8-col chunk cq = l&3)
        {
            int m = l >> 2, cq = l & 3;
            s16x8 pv;
#pragma unroll
            for (int jj = 0; jj < 8; ++jj)
                pv[jj] = (short)f2b(gbuf[w][m][cq * 8 + jj]);
            *(s16x8*)(out + (size_t)(row0 + m) * G4 + nw + cq * 8) = pv;
        }
        __syncthreads();
    }
}

// ---------------------------------------------------------------------------
// Recurrent sweep: one block per (batch-pair, dir). 4 waves; wave w owns gate w
// (128 gate-cols = 8 N-tiles). W_hh B-frags pinned in 128 VGPRs (bf16).
// gx: [2][B*T][512] bf16 (input contributions, no bias). y: [B][T][256] fp32.
// ---------------------------------------------------------------------------
__global__ __launch_bounds__(256, 1)
void lstm_rec(const unsigned short* __restrict__ gx,
              const float* __restrict__ Whf,
              const float* __restrict__ Whb,
              const float* __restrict__ biasf,
              const float* __restrict__ biasb,
              float* __restrict__ y,
              float* __restrict__ hn,
              float* __restrict__ cn,
              int layer)
{
    const int b0  = blockIdx.x * 2;
    const int dir = blockIdx.y;
    const float* Wh   = dir ? Whb : Whf;
    const float* bias = dir ? biasb : biasf;
    const unsigned short* gxd = gx + (size_t)dir * Bn * Tn * G4;

    const int tid = threadIdx.x;
    const int w = tid >> 6, l = tid & 63;
    const int q = l >> 4, i = l & 15;

    __shared__ unsigned short hbuf[16][136];  // h_prev bf16, A-frag source
    __shared__ float Gs[512][2];              // recurrent gate contribs, m=0,1

    for (int idx = tid; idx < 16 * 136; idx += 256)
        ((unsigned short*)hbuf)[idx] = 0;

    // W_hh B-frags: B[k][n] = W_hh[n][k]; lane: n = w*128+nt*16+i, k = kf*32+q*8
    s16x8 wh[8][4];
#pragma unroll
    for (int nt = 0; nt < 8; ++nt) {
        int n = w * 128 + nt * 16 + i;
#pragma unroll
        for (int kf = 0; kf < 4; ++kf)
            wh[nt][kf] = cvt8v(Wh + (size_t)n * Hn + kf * 32 + q * 8);
    }

    // per-thread cell: m in {0,1}, hidden index j
    const int m = tid >> 7;
    const int j = tid & 127;
    const int b = b0 + m;
    const float bi = bias[j],       bf = bias[128 + j];
    const float bg = bias[256 + j], bo = bias[384 + j];
    float c = 0.f, hlast = 0.f;

    // prefetch gx for step 0
    const int t0 = dir ? (Tn - 1) : 0;
    const unsigned short* gr0 = gxd + ((size_t)b * Tn + t0) * G4;
    float pgi = b2f(gr0[j]),       pgf = b2f(gr0[128 + j]);
    float pgg = b2f(gr0[256 + j]), pgo = b2f(gr0[384 + j]);

    __syncthreads();

    for (int s = 0; s < Tn; ++s) {
        const int t = dir ? (Tn - 1 - s) : s;

        // MFMA: gates[0:16][n] = h @ W_hh^T   (rows >= 2 are zero/unused)
        s16x8 ah[4];
#pragma unroll
        for (int kf = 0; kf < 4; ++kf)
            ah[kf] = *(const s16x8*)(&hbuf[i][kf * 32 + q * 8]);
        f32x4 acc[8];
#pragma unroll
        for (int nt = 0; nt < 8; ++nt) {
            acc[nt] = f32x4{0.f,0.f,0.f,0.f};
#pragma unroll
            for (int kf = 0; kf < 4; ++kf)
                acc[nt] = __builtin_amdgcn_mfma_f32_16x16x32_bf16(ah[kf], wh[nt][kf], acc[nt], 0, 0, 0);
        }
        // rows m=0,1 live in q==0 lanes' regs 0,1
        if (q == 0) {
#pragma unroll
            for (int nt = 0; nt < 8; ++nt) {
                int n = w * 128 + nt * 16 + i;
                Gs[n][0] = acc[nt][0];
                Gs[n][1] = acc[nt][1];
            }
        }
        __syncthreads();

        // cell update (fp32 state)
        float gi = Gs[j][m]       + pgi + bi;
        float gf = Gs[128 + j][m] + pgf + bf;
        float gg = Gs[256 + j][m] + pgg + bg;
        float go = Gs[384 + j][m] + pgo + bo;
        float iv = sigm(gi), fv = sigm(gf), ov = sigm(go);
        float gv = tanh_f(gg);
        c = fv * c + iv * gv;
        float h = ov * tanh_f(c);
        hlast = h;
        hbuf[m][j] = f2b(h);
        y[((size_t)b * Tn + t) * 256 + dir * 128 + j] = h;

        // prefetch next step's gx
        int s2 = (s + 1 < Tn) ? (s + 1) : s;
        int t2 = dir ? (Tn - 1 - s2) : s2;
        const unsigned short* gp = gxd + ((size_t)b * Tn + t2) * G4;
        pgi = b2f(gp[j]);       pgf = b2f(gp[128 + j]);
        pgg = b2f(gp[256 + j]); pgo = b2f(gp[384 + j]);
        __syncthreads();
    }

    const int slot = layer * 2 + dir;
    hn[((size_t)slot * Bn + b) * Hn + j] = hlast;
    cn[((size_t)slot * Bn + b) * Hn + j] = c;
}

// ---------------------------------------------------------------------------
extern "C" void kernel_launch(void* const* d_in, const int* in_sizes, int n_in,
                              void* d_out, int out_size, void* d_ws, size_t ws_size,
                              hipStream_t stream)
{
    const float* x     = (const float*)d_in[0];
    const float* wih0f = (const float*)d_in[1];
    const float* whh0f = (const float*)d_in[2];
    const float* b0f   = (const float*)d_in[3];
    const float* wih0b = (const float*)d_in[4];
    const float* whh0b = (const float*)d_in[5];
    const float* b0b   = (const float*)d_in[6];
    const float* wih1f = (const float*)d_in[7];
    const float* whh1f = (const float*)d_in[8];
    const float* b1f   = (const float*)d_in[9];
    const float* wih1b = (const float*)d_in[10];
    const float* whh1b = (const float*)d_in[11];
    const float* b1b   = (const float*)d_in[12];

    float* y  = (float*)d_out;                     // [B][T][256] fp32
    float* hn = y + (size_t)Bn * Tn * 256;         // [4][B][128]
    float* cn = hn + (size_t)4 * Bn * Hn;          // [4][B][128]
    unsigned short* gx = (unsigned short*)d_ws;    // [2][B*T][512] bf16 = 256 MiB

    dim3 gg(128, 8), gb(256);
    dim3 rg(128, 2), rb(256);

    // layer 0: gx0 = x @ W_ih0^T (K=24) -> rec sweep writes y0 (fp32) into d_out
    gemm_gx<24, 24><<<gg, gb, 0, stream>>>(x, wih0f, wih0b, gx);
    lstm_rec<<<rg, rb, 0, stream>>>(gx, whh0f, whh0b, b0f, b0b, y, hn, cn, 0);
    // layer 1: gx1 = y0 @ W_ih1^T (K=256) -> rec sweep overwrites y with y1
    gemm_gx<256, 256><<<gg, gb, 0, stream>>>(y, wih1f, wih1b, gx);
    lstm_rec<<<rg, rb, 0, stream>>>(gx, whh1f, whh1b, b1f, b1b, y, hn, cn, 1);
}

// Round 4
// 1107.039 us; speedup vs baseline: 1.2850x; 1.2850x over previous
//
#include <hip/hip_runtime.h>
#include <hip/hip_bf16.h>
#include <stdint.h>

#define Bn 256
#define Tn 512
#define Hn 128
#define G4 512   // 4*H
#define Mn (Bn*Tn)

typedef __attribute__((ext_vector_type(8))) short s16x8;
typedef __attribute__((ext_vector_type(4))) float f32x4;

__device__ __forceinline__ float b2f(unsigned short u) {
    union { unsigned int i; float f; } v; v.i = ((unsigned int)u) << 16; return v.f;
}
__device__ __forceinline__ unsigned short f2b(float f) {
    union { float f; unsigned int i; } v; v.f = f;
    unsigned int x = v.i;
    unsigned int r = (x + 0x7FFFu + ((x >> 16) & 1u)) >> 16;
    return (unsigned short)r;
}
// packed fp32x2 -> bf16x2 (RNE)
__device__ __forceinline__ unsigned int pk2(float a, float b) {
    __hip_bfloat162 t = __float22bfloat162_rn(make_float2(a, b));
    union { __hip_bfloat162 v; unsigned int u; } c; c.v = t; return c.u;
}
// 8 consecutive fp32 -> bf16 fragment (used by rec for W_hh, once per block)
__device__ __forceinline__ s16x8 cvt8v(const float* p) {
    f32x4 a = *(const f32x4*)p;
    f32x4 b = *(const f32x4*)(p + 4);
    s16x8 r;
    r[0] = (short)f2b(a[0]); r[1] = (short)f2b(a[1]);
    r[2] = (short)f2b(a[2]); r[3] = (short)f2b(a[3]);
    r[4] = (short)f2b(b[0]); r[5] = (short)f2b(b[1]);
    r[6] = (short)f2b(b[2]); r[7] = (short)f2b(b[3]);
    return r;
}
__device__ __forceinline__ float sigm(float x) {
    return __builtin_amdgcn_rcpf(1.f + __expf(-x));
}
__device__ __forceinline__ float tanh_f(float x) {
    return 1.f - 2.f * __builtin_amdgcn_rcpf(1.f + __expf(2.f * x));
}
__device__ __forceinline__ void gload16(const void* gsrc, void* lds) {
    __builtin_amdgcn_global_load_lds(
        (const __attribute__((address_space(1))) unsigned int*)gsrc,
        (__attribute__((address_space(3))) unsigned int*)lds, 16, 0, 0);
}

// ---------------------------------------------------------------------------
// prep: fp32 -> bf16 conversions into d_out scratch (y1 region, written last)
//   xb   [M][32]       : x zero-padded K 24->32
//   w0bf [2][512][32]  : W_ih0 {f,b} zero-padded
//   w1bf [2][512][256] : W_ih1 {f,b}
// ---------------------------------------------------------------------------
__global__ __launch_bounds__(256)
void prep(const float* __restrict__ x,
          const float* __restrict__ w0f, const float* __restrict__ w0b,
          const float* __restrict__ w1f, const float* __restrict__ w1b,
          unsigned short* __restrict__ xb,
          unsigned short* __restrict__ w0bf,
          unsigned short* __restrict__ w1bf)
{
    int tid = blockIdx.x * 256 + threadIdx.x;
    int nthr = gridDim.x * 256;
    for (int idx = tid; idx < Mn * 32; idx += nthr) {
        int row = idx >> 5, col = idx & 31;
        xb[idx] = f2b(col < 24 ? x[row * 24 + col] : 0.f);
    }
    for (int idx = tid; idx < 2 * 512 * 32; idx += nthr) {
        int d = idx >> 14, rem = idx & 16383;
        int n = rem >> 5, col = rem & 31;
        const float* w = d ? w0b : w0f;
        w0bf[idx] = f2b(col < 24 ? w[n * 24 + col] : 0.f);
    }
    for (int idx = tid; idx < 2 * 512 * 256; idx += nthr) {
        int d = idx >> 17, rem = idx & 131071;
        const float* w = d ? w1b : w1f;
        w1bf[idx] = f2b(w[rem]);
    }
}

// ---------------------------------------------------------------------------
// Tiled GEMM: gx[dir][m][n] = sum_k A[m][k]*W[dir][n][k]  (all bf16 in/out)
// 128x128 tile, K staged in BK-chunks via global_load_lds (16B, XOR-swizzled).
// ---------------------------------------------------------------------------
template<int BK, int KOUT>
__global__ __launch_bounds__(256, 2)
void gemm_tile(const unsigned short* __restrict__ A, int lda,
               const unsigned short* __restrict__ W,   // [2][512][BK*KOUT]
               unsigned short* __restrict__ gx)
{
    constexpr int GR = BK / 8;                  // 16B granules per row-chunk
    constexpr int SWM = (GR >= 8) ? 7 : (GR - 1);
    constexpr int ASZ = 128 * BK * 2;           // bytes per tile
    constexpr int GOFF = (BK == 128) ? 0 : 2 * ASZ;   // gbuf overlay for BK=128
    constexpr int SMEM = 2 * ASZ + ((BK == 128) ? 0 : 4 * 16 * 68 * 4);
    __shared__ char smem[SMEM];
    unsigned short* Atile = (unsigned short*)smem;
    unsigned short* Btile = (unsigned short*)(smem + ASZ);

    const int K = BK * KOUT;
    const int mb = blockIdx.x;              // 0..1023
    const int nb = blockIdx.y;              // 0..7
    const int dir = nb >> 2, ncol0 = (nb & 3) * 128;
    const int row0 = mb * 128;
    const unsigned short* Asrc = A + (size_t)row0 * lda;
    const unsigned short* Bsrc = W + (size_t)dir * 512 * K + (size_t)ncol0 * K;
    unsigned short* out = gx + (size_t)dir * Mn * G4;

    const int tid = threadIdx.x;
    const int w = tid >> 6, l = tid & 63;
    const int q = l >> 4, i = l & 15;
    const int wm = w >> 1, wn = w & 1;      // 64x64 per wave

    f32x4 acc[4][4];
#pragma unroll
    for (int a = 0; a < 4; ++a)
#pragma unroll
        for (int b = 0; b < 4; ++b) acc[a][b] = f32x4{0.f, 0.f, 0.f, 0.f};

    for (int ko = 0; ko < KOUT; ++ko) {
        // stage A & B chunk: swizzled source granule -> linear LDS granule
#pragma unroll
        for (int it = 0; it < (128 * GR) / 256; ++it) {
            int g = it * 256 + tid;
            int row = g / GR, p = g % GR;
            int gi = p ^ (row & SWM);
            gload16(Asrc + (size_t)row * lda + ko * BK + gi * 8,
                    (char*)Atile + g * 16);
        }
#pragma unroll
        for (int it = 0; it < (128 * GR) / 256; ++it) {
            int g = it * 256 + tid;
            int row = g / GR, p = g % GR;
            int gi = p ^ (row & SWM);
            gload16(Bsrc + (size_t)row * K + ko * BK + gi * 8,
                    (char*)Btile + g * 16);
        }
        __syncthreads();
#pragma unroll
        for (int kf = 0; kf < BK / 32; ++kf) {
            s16x8 af[4], bf[4];
#pragma unroll
            for (int mt = 0; mt < 4; ++mt) {
                int ar = wm * 64 + mt * 16 + i;
                int p = (kf * 4 + q) ^ (ar & SWM);
                af[mt] = *(const s16x8*)((char*)Atile + (ar * GR + p) * 16);
            }
#pragma unroll
            for (int nt = 0; nt < 4; ++nt) {
                int br = wn * 64 + nt * 16 + i;
                int p = (kf * 4 + q) ^ (br & SWM);
                bf[nt] = *(const s16x8*)((char*)Btile + (br * GR + p) * 16);
            }
#pragma unroll
            for (int mt = 0; mt < 4; ++mt)
#pragma unroll
                for (int nt = 0; nt < 4; ++nt)
                    acc[mt][nt] = __builtin_amdgcn_mfma_f32_16x16x32_bf16(
                        af[mt], bf[nt], acc[mt][nt], 0, 0, 0);
        }
        __syncthreads();
    }

    // epilogue: LDS repack (per-wave) -> packed bf16 -> coalesced 16B stores
    float* gbufw = (float*)(smem + GOFF) + w * (16 * 68);
#pragma unroll
    for (int mt = 0; mt < 4; ++mt) {
#pragma unroll
        for (int nt = 0; nt < 4; ++nt)
#pragma unroll
            for (int r = 0; r < 4; ++r)
                gbufw[(q * 4 + r) * 68 + nt * 16 + i] = acc[mt][nt][r];
        __syncthreads();
#pragma unroll
        for (int it2 = 0; it2 < 2; ++it2) {
            int rr = (l >> 3) + it2 * 8;
            int cc = (l & 7) * 8;
            const float* gsrc = gbufw + rr * 68 + cc;
            uint4 pv;
            pv.x = pk2(gsrc[0], gsrc[1]);
            pv.y = pk2(gsrc[2], gsrc[3]);
            pv.z = pk2(gsrc[4], gsrc[5]);
            pv.w = pk2(gsrc[6], gsrc[7]);
            // FIX (round 4): row must include the wave's M-offset wm*64.
            *(uint4*)(out + (size_t)(row0 + wm * 64 + mt * 16 + rr) * G4
                          + ncol0 + wn * 64 + cc) = pv;
        }
        __syncthreads();
    }
}

// ---------------------------------------------------------------------------
// Recurrent sweep: one block per (batch-pair, dir); wave w owns gate w.
// layer0 emits y0 bf16 to scratch, layer1 emits y1 fp32 to d_out.
// ---------------------------------------------------------------------------
__global__ __launch_bounds__(256, 1)
void lstm_rec(const unsigned short* __restrict__ gx,
              const float* __restrict__ Whf,
              const float* __restrict__ Whb,
              const float* __restrict__ biasf,
              const float* __restrict__ biasb,
              float* __restrict__ y,
              unsigned short* __restrict__ y0b,
              float* __restrict__ hn,
              float* __restrict__ cn,
              int layer)
{
    const int b0  = blockIdx.x * 2;
    const int dir = blockIdx.y;
    const float* Wh   = dir ? Whb : Whf;
    const float* bias = dir ? biasb : biasf;
    const unsigned short* gxd = gx + (size_t)dir * Mn * G4;

    const int tid = threadIdx.x;
    const int w = tid >> 6, l = tid & 63;
    const int q = l >> 4, i = l & 15;

    __shared__ unsigned short hbuf[16][136];
    __shared__ float Gs[512][2];

    for (int idx = tid; idx < 16 * 136; idx += 256)
        ((unsigned short*)hbuf)[idx] = 0;

    s16x8 wh[8][4];
#pragma unroll
    for (int nt = 0; nt < 8; ++nt) {
        int n = w * 128 + nt * 16 + i;
#pragma unroll
        for (int kf = 0; kf < 4; ++kf)
            wh[nt][kf] = cvt8v(Wh + (size_t)n * Hn + kf * 32 + q * 8);
    }

    const int m = tid >> 7;
    const int j = tid & 127;
    const int b = b0 + m;
    const float bi = bias[j],       bf = bias[128 + j];
    const float bg = bias[256 + j], bo = bias[384 + j];
    float c = 0.f, hlast = 0.f;

    const int t0 = dir ? (Tn - 1) : 0;
    const unsigned short* gr0 = gxd + ((size_t)b * Tn + t0) * G4;
    float pgi = b2f(gr0[j]),       pgf = b2f(gr0[128 + j]);
    float pgg = b2f(gr0[256 + j]), pgo = b2f(gr0[384 + j]);

    __syncthreads();

    for (int s = 0; s < Tn; ++s) {
        const int t = dir ? (Tn - 1 - s) : s;

        s16x8 ah[4];
#pragma unroll
        for (int kf = 0; kf < 4; ++kf)
            ah[kf] = *(const s16x8*)(&hbuf[i][kf * 32 + q * 8]);
        f32x4 acc[8];
#pragma unroll
        for (int nt = 0; nt < 8; ++nt) {
            acc[nt] = f32x4{0.f, 0.f, 0.f, 0.f};
#pragma unroll
            for (int kf = 0; kf < 4; ++kf)
                acc[nt] = __builtin_amdgcn_mfma_f32_16x16x32_bf16(ah[kf], wh[nt][kf], acc[nt], 0, 0, 0);
        }
        if (q == 0) {
#pragma unroll
            for (int nt = 0; nt < 8; ++nt) {
                int n = w * 128 + nt * 16 + i;
                Gs[n][0] = acc[nt][0];
                Gs[n][1] = acc[nt][1];
            }
        }
        __syncthreads();

        float gi = Gs[j][m]       + pgi + bi;
        float gf = Gs[128 + j][m] + pgf + bf;
        float gg = Gs[256 + j][m] + pgg + bg;
        float go = Gs[384 + j][m] + pgo + bo;
        float iv = sigm(gi), fv = sigm(gf), ov = sigm(go);
        float gv = tanh_f(gg);
        c = fv * c + iv * gv;
        float h = ov * tanh_f(c);
        hlast = h;
        unsigned short hb = f2b(h);
        hbuf[m][j] = hb;
        if (layer == 0)
            y0b[((size_t)b * Tn + t) * 256 + dir * 128 + j] = hb;
        else
            y[((size_t)b * Tn + t) * 256 + dir * 128 + j] = h;

        int s2 = (s + 1 < Tn) ? (s + 1) : s;
        int t2 = dir ? (Tn - 1 - s2) : s2;
        const unsigned short* gp = gxd + ((size_t)b * Tn + t2) * G4;
        pgi = b2f(gp[j]);       pgf = b2f(gp[128 + j]);
        pgg = b2f(gp[256 + j]); pgo = b2f(gp[384 + j]);
        __syncthreads();
    }

    const int slot = layer * 2 + dir;
    hn[((size_t)slot * Bn + b) * Hn + j] = hlast;
    cn[((size_t)slot * Bn + b) * Hn + j] = c;
}

// ---------------------------------------------------------------------------
extern "C" void kernel_launch(void* const* d_in, const int* in_sizes, int n_in,
                              void* d_out, int out_size, void* d_ws, size_t ws_size,
                              hipStream_t stream)
{
    const float* x     = (const float*)d_in[0];
    const float* wih0f = (const float*)d_in[1];
    const float* whh0f = (const float*)d_in[2];
    const float* b0f   = (const float*)d_in[3];
    const float* wih0b = (const float*)d_in[4];
    const float* whh0b = (const float*)d_in[5];
    const float* b0b   = (const float*)d_in[6];
    const float* wih1f = (const float*)d_in[7];
    const float* whh1f = (const float*)d_in[8];
    const float* b1f   = (const float*)d_in[9];
    const float* wih1b = (const float*)d_in[10];
    const float* whh1b = (const float*)d_in[11];
    const float* b1b   = (const float*)d_in[12];

    float* y  = (float*)d_out;                       // [B][T][256] fp32 (final)
    float* hn = y + (size_t)Mn * 256;                // [4][B][128]
    float* cn = hn + (size_t)4 * Bn * Hn;            // [4][B][128]
    unsigned short* gx = (unsigned short*)d_ws;      // [2][M][512] bf16 = 256 MiB

    // scratch inside d_out's y1 region (y1 written last, by rec layer 1):
    unsigned short* scr  = (unsigned short*)d_out;
    unsigned short* y0b  = scr;                              // [M][256] bf16
    unsigned short* xb   = scr + (size_t)Mn * 256;           // [M][32]
    unsigned short* w0bf = xb  + (size_t)Mn * 32;            // [2][512][32]
    unsigned short* w1bf = w0bf + 2 * 512 * 32;              // [2][512][256]

    prep<<<2048, 256, 0, stream>>>(x, wih0f, wih0b, wih1f, wih1b, xb, w0bf, w1bf);

    dim3 gg(1024, 8), gb(256);
    dim3 rg(128, 2), rb(256);

    gemm_tile<32, 1><<<gg, gb, 0, stream>>>(xb, 32, w0bf, gx);
    lstm_rec<<<rg, rb, 0, stream>>>(gx, whh0f, whh0b, b0f, b0b, y, y0b, hn, cn, 0);
    gemm_tile<128, 2><<<gg, gb, 0, stream>>>(y0b, 256, w1bf, gx);
    lstm_rec<<<rg, rb, 0, stream>>>(gx, whh1f, whh1b, b1f, b1b, y, y0b, hn, cn, 1);
}

// Round 5
// 1003.814 us; speedup vs baseline: 1.4172x; 1.1028x over previous
//
#include <hip/hip_runtime.h>
#include <hip/hip_bf16.h>
#include <stdint.h>

#define Bn 256
#define Tn 512
#define Hn 128
#define G4 512   // 4*H
#define Mn (Bn*Tn)

typedef __attribute__((ext_vector_type(8))) short s16x8;
typedef __attribute__((ext_vector_type(4))) float f32x4;

__device__ __forceinline__ float b2f(unsigned short u) {
    union { unsigned int i; float f; } v; v.i = ((unsigned int)u) << 16; return v.f;
}
__device__ __forceinline__ unsigned short f2b(float f) {
    union { float f; unsigned int i; } v; v.f = f;
    unsigned int x = v.i;
    unsigned int r = (x + 0x7FFFu + ((x >> 16) & 1u)) >> 16;
    return (unsigned short)r;
}
// packed fp32x2 -> bf16x2 (RNE)
__device__ __forceinline__ unsigned int pk2(float a, float b) {
    __hip_bfloat162 t = __float22bfloat162_rn(make_float2(a, b));
    union { __hip_bfloat162 v; unsigned int u; } c; c.v = t; return c.u;
}
// 8 consecutive fp32 -> bf16 fragment (used by rec for W_hh, once per block)
__device__ __forceinline__ s16x8 cvt8v(const float* p) {
    f32x4 a = *(const f32x4*)p;
    f32x4 b = *(const f32x4*)(p + 4);
    s16x8 r;
    r[0] = (short)f2b(a[0]); r[1] = (short)f2b(a[1]);
    r[2] = (short)f2b(a[2]); r[3] = (short)f2b(a[3]);
    r[4] = (short)f2b(b[0]); r[5] = (short)f2b(b[1]);
    r[6] = (short)f2b(b[2]); r[7] = (short)f2b(b[3]);
    return r;
}
__device__ __forceinline__ float sigm(float x) {
    return __builtin_amdgcn_rcpf(1.f + __expf(-x));
}
__device__ __forceinline__ float tanh_f(float x) {
    return 1.f - 2.f * __builtin_amdgcn_rcpf(1.f + __expf(2.f * x));
}
__device__ __forceinline__ void gload16(const void* gsrc, void* lds) {
    __builtin_amdgcn_global_load_lds(
        (const __attribute__((address_space(1))) unsigned int*)gsrc,
        (__attribute__((address_space(3))) unsigned int*)lds, 16, 0, 0);
}
// LDS-only barrier: waits DS ops but NOT outstanding global loads/stores.
// Safe when inter-wave communication is exclusively through LDS.
__device__ __forceinline__ void ldsbar() {
    asm volatile("s_waitcnt lgkmcnt(0)\n\ts_barrier" ::: "memory");
}

// ---------------------------------------------------------------------------
// prep: fp32 -> bf16 conversions into d_out scratch (y1 region, written last)
// ---------------------------------------------------------------------------
__global__ __launch_bounds__(256)
void prep(const float* __restrict__ x,
          const float* __restrict__ w0f, const float* __restrict__ w0b,
          const float* __restrict__ w1f, const float* __restrict__ w1b,
          unsigned short* __restrict__ xb,
          unsigned short* __restrict__ w0bf,
          unsigned short* __restrict__ w1bf)
{
    int tid = blockIdx.x * 256 + threadIdx.x;
    int nthr = gridDim.x * 256;
    for (int idx = tid; idx < Mn * 32; idx += nthr) {
        int row = idx >> 5, col = idx & 31;
        xb[idx] = f2b(col < 24 ? x[row * 24 + col] : 0.f);
    }
    for (int idx = tid; idx < 2 * 512 * 32; idx += nthr) {
        int d = idx >> 14, rem = idx & 16383;
        int n = rem >> 5, col = rem & 31;
        const float* w = d ? w0b : w0f;
        w0bf[idx] = f2b(col < 24 ? w[n * 24 + col] : 0.f);
    }
    for (int idx = tid; idx < 2 * 512 * 256; idx += nthr) {
        int d = idx >> 17, rem = idx & 131071;
        const float* w = d ? w1b : w1f;
        w1bf[idx] = f2b(w[rem]);
    }
}

// ---------------------------------------------------------------------------
// Tiled GEMM (unchanged from round 4, passing): gx[dir][m][n] = A@W^T, bf16.
// ---------------------------------------------------------------------------
template<int BK, int KOUT>
__global__ __launch_bounds__(256, 2)
void gemm_tile(const unsigned short* __restrict__ A, int lda,
               const unsigned short* __restrict__ W,   // [2][512][BK*KOUT]
               unsigned short* __restrict__ gx)
{
    constexpr int GR = BK / 8;
    constexpr int SWM = (GR >= 8) ? 7 : (GR - 1);
    constexpr int ASZ = 128 * BK * 2;
    constexpr int GOFF = (BK == 128) ? 0 : 2 * ASZ;
    constexpr int SMEM = 2 * ASZ + ((BK == 128) ? 0 : 4 * 16 * 68 * 4);
    __shared__ char smem[SMEM];
    unsigned short* Atile = (unsigned short*)smem;
    unsigned short* Btile = (unsigned short*)(smem + ASZ);

    const int K = BK * KOUT;
    const int mb = blockIdx.x;
    const int nb = blockIdx.y;
    const int dir = nb >> 2, ncol0 = (nb & 3) * 128;
    const int row0 = mb * 128;
    const unsigned short* Asrc = A + (size_t)row0 * lda;
    const unsigned short* Bsrc = W + (size_t)dir * 512 * K + (size_t)ncol0 * K;
    unsigned short* out = gx + (size_t)dir * Mn * G4;

    const int tid = threadIdx.x;
    const int w = tid >> 6, l = tid & 63;
    const int q = l >> 4, i = l & 15;
    const int wm = w >> 1, wn = w & 1;

    f32x4 acc[4][4];
#pragma unroll
    for (int a = 0; a < 4; ++a)
#pragma unroll
        for (int b = 0; b < 4; ++b) acc[a][b] = f32x4{0.f, 0.f, 0.f, 0.f};

    for (int ko = 0; ko < KOUT; ++ko) {
#pragma unroll
        for (int it = 0; it < (128 * GR) / 256; ++it) {
            int g = it * 256 + tid;
            int row = g / GR, p = g % GR;
            int gi = p ^ (row & SWM);
            gload16(Asrc + (size_t)row * lda + ko * BK + gi * 8,
                    (char*)Atile + g * 16);
        }
#pragma unroll
        for (int it = 0; it < (128 * GR) / 256; ++it) {
            int g = it * 256 + tid;
            int row = g / GR, p = g % GR;
            int gi = p ^ (row & SWM);
            gload16(Bsrc + (size_t)row * K + ko * BK + gi * 8,
                    (char*)Btile + g * 16);
        }
        __syncthreads();   // must drain vmcnt (global_load_lds) — keep full sync
#pragma unroll
        for (int kf = 0; kf < BK / 32; ++kf) {
            s16x8 af[4], bf[4];
#pragma unroll
            for (int mt = 0; mt < 4; ++mt) {
                int ar = wm * 64 + mt * 16 + i;
                int p = (kf * 4 + q) ^ (ar & SWM);
                af[mt] = *(const s16x8*)((char*)Atile + (ar * GR + p) * 16);
            }
#pragma unroll
            for (int nt = 0; nt < 4; ++nt) {
                int br = wn * 64 + nt * 16 + i;
                int p = (kf * 4 + q) ^ (br & SWM);
                bf[nt] = *(const s16x8*)((char*)Btile + (br * GR + p) * 16);
            }
#pragma unroll
            for (int mt = 0; mt < 4; ++mt)
#pragma unroll
                for (int nt = 0; nt < 4; ++nt)
                    acc[mt][nt] = __builtin_amdgcn_mfma_f32_16x16x32_bf16(
                        af[mt], bf[nt], acc[mt][nt], 0, 0, 0);
        }
        __syncthreads();
    }

    float* gbufw = (float*)(smem + GOFF) + w * (16 * 68);
#pragma unroll
    for (int mt = 0; mt < 4; ++mt) {
#pragma unroll
        for (int nt = 0; nt < 4; ++nt)
#pragma unroll
            for (int r = 0; r < 4; ++r)
                gbufw[(q * 4 + r) * 68 + nt * 16 + i] = acc[mt][nt][r];
        __syncthreads();
#pragma unroll
        for (int it2 = 0; it2 < 2; ++it2) {
            int rr = (l >> 3) + it2 * 8;
            int cc = (l & 7) * 8;
            const float* gsrc = gbufw + rr * 68 + cc;
            uint4 pv;
            pv.x = pk2(gsrc[0], gsrc[1]);
            pv.y = pk2(gsrc[2], gsrc[3]);
            pv.z = pk2(gsrc[4], gsrc[5]);
            pv.w = pk2(gsrc[6], gsrc[7]);
            *(uint4*)(out + (size_t)(row0 + wm * 64 + mt * 16 + rr) * G4
                          + ncol0 + wn * 64 + cc) = pv;
        }
        __syncthreads();
    }
}

// ---------------------------------------------------------------------------
// Recurrent sweep v2: LDS-only barriers + 8-step-ahead gx register prefetch.
// One block per (batch-pair, dir); wave w owns gate w; W_hh frags in regs.
// ---------------------------------------------------------------------------
__global__ __launch_bounds__(256, 1)
void lstm_rec(const unsigned short* __restrict__ gx,
              const float* __restrict__ Whf,
              const float* __restrict__ Whb,
              const float* __restrict__ biasf,
              const float* __restrict__ biasb,
              float* __restrict__ y,
              unsigned short* __restrict__ y0b,
              float* __restrict__ hn,
              float* __restrict__ cn,
              int layer)
{
    const int b0  = blockIdx.x * 2;
    const int dir = blockIdx.y;
    const float* Wh   = dir ? Whb : Whf;
    const float* bias = dir ? biasb : biasf;
    const unsigned short* gxd = gx + (size_t)dir * Mn * G4;

    const int tid = threadIdx.x;
    const int w = tid >> 6, l = tid & 63;
    const int q = l >> 4, i = l & 15;

    __shared__ unsigned short hbuf[16][136];
    __shared__ float Gs[512][2];

    for (int idx = tid; idx < 16 * 136; idx += 256)
        ((unsigned short*)hbuf)[idx] = 0;

    s16x8 wh[8][4];
#pragma unroll
    for (int nt = 0; nt < 8; ++nt) {
        int n = w * 128 + nt * 16 + i;
#pragma unroll
        for (int kf = 0; kf < 4; ++kf)
            wh[nt][kf] = cvt8v(Wh + (size_t)n * Hn + kf * 32 + q * 8);
    }

    const int m = tid >> 7;
    const int j = tid & 127;
    const int b = b0 + m;
    const float bi = bias[j],       bf = bias[128 + j];
    const float bg = bias[256 + j], bo = bias[384 + j];
    float c = 0.f, hlast = 0.f;

    // gx prefetch double-buffer: raw bf16 bits, converted only at use so the
    // compiler's vmcnt wait lands ~8 steps after issue.
    unsigned short bufA[4][8], bufB[4][8];
#pragma unroll
    for (int f = 0; f < 8; ++f) {
        int t = dir ? (Tn - 1 - f) : f;
        const unsigned short* gp = gxd + ((size_t)b * Tn + t) * G4;
        bufA[0][f] = gp[j];
        bufA[1][f] = gp[128 + j];
        bufA[2][f] = gp[256 + j];
        bufA[3][f] = gp[384 + j];
    }

    __syncthreads();   // once: covers hbuf zero-init

    auto do8 = [&](unsigned short (&useB)[4][8], unsigned short (&ldB)[4][8],
                   int sb) {
#pragma unroll
        for (int f = 0; f < 8; ++f) {
            const int s = sb + f;
            const int t = dir ? (Tn - 1 - s) : s;

            // MFMA phase: gates[n] = h @ W_hh^T (M rows 0,1 used)
            s16x8 ah[4];
#pragma unroll
            for (int kf = 0; kf < 4; ++kf)
                ah[kf] = *(const s16x8*)(&hbuf[i][kf * 32 + q * 8]);
            f32x4 acc[8];
#pragma unroll
            for (int nt = 0; nt < 8; ++nt) {
                acc[nt] = f32x4{0.f, 0.f, 0.f, 0.f};
#pragma unroll
                for (int kf = 0; kf < 4; ++kf)
                    acc[nt] = __builtin_amdgcn_mfma_f32_16x16x32_bf16(
                        ah[kf], wh[nt][kf], acc[nt], 0, 0, 0);
            }
            if (q == 0) {
#pragma unroll
                for (int nt = 0; nt < 8; ++nt) {
                    int n = w * 128 + nt * 16 + i;
                    Gs[n][0] = acc[nt][0];
                    Gs[n][1] = acc[nt][1];
                }
            }
            // issue gx prefetch for step s+8 (used 8 steps from now)
            {
                int sl = (s + 8 < Tn) ? (s + 8) : s;
                int tl = dir ? (Tn - 1 - sl) : sl;
                const unsigned short* gp = gxd + ((size_t)b * Tn + tl) * G4;
                ldB[0][f] = gp[j];
                ldB[1][f] = gp[128 + j];
                ldB[2][f] = gp[256 + j];
                ldB[3][f] = gp[384 + j];
            }
            ldsbar();   // barrier 1: Gs write -> Gs read (LDS only)

            float gi = Gs[j][m]       + b2f(useB[0][f]) + bi;
            float gf = Gs[128 + j][m] + b2f(useB[1][f]) + bf;
            float gg = Gs[256 + j][m] + b2f(useB[2][f]) + bg;
            float go = Gs[384 + j][m] + b2f(useB[3][f]) + bo;
            float iv = sigm(gi), fv = sigm(gf), ov = sigm(go);
            float gv = tanh_f(gg);
            c = fv * c + iv * gv;
            float h = ov * tanh_f(c);
            hlast = h;
            unsigned short hb = f2b(h);
            hbuf[m][j] = hb;
            if (layer == 0)
                y0b[((size_t)b * Tn + t) * 256 + dir * 128 + j] = hb;   // fire-and-forget
            else
                y[((size_t)b * Tn + t) * 256 + dir * 128 + j] = h;

            ldsbar();   // barrier 2: hbuf write -> next step's A-frag read
        }
    };

    for (int sb = 0; sb < Tn; sb += 16) {
        do8(bufA, bufB, sb);
        do8(bufB, bufA, sb + 8);
    }

    const int slot = layer * 2 + dir;
    hn[((size_t)slot * Bn + b) * Hn + j] = hlast;
    cn[((size_t)slot * Bn + b) * Hn + j] = c;
}

// ---------------------------------------------------------------------------
extern "C" void kernel_launch(void* const* d_in, const int* in_sizes, int n_in,
                              void* d_out, int out_size, void* d_ws, size_t ws_size,
                              hipStream_t stream)
{
    const float* x     = (const float*)d_in[0];
    const float* wih0f = (const float*)d_in[1];
    const float* whh0f = (const float*)d_in[2];
    const float* b0f   = (const float*)d_in[3];
    const float* wih0b = (const float*)d_in[4];
    const float* whh0b = (const float*)d_in[5];
    const float* b0b   = (const float*)d_in[6];
    const float* wih1f = (const float*)d_in[7];
    const float* whh1f = (const float*)d_in[8];
    const float* b1f   = (const float*)d_in[9];
    const float* wih1b = (const float*)d_in[10];
    const float* whh1b = (const float*)d_in[11];
    const float* b1b   = (const float*)d_in[12];

    float* y  = (float*)d_out;                       // [B][T][256] fp32 (final)
    float* hn = y + (size_t)Mn * 256;                // [4][B][128]
    float* cn = hn + (size_t)4 * Bn * Hn;            // [4][B][128]
    unsigned short* gx = (unsigned short*)d_ws;      // [2][M][512] bf16 = 256 MiB

    unsigned short* scr  = (unsigned short*)d_out;
    unsigned short* y0b  = scr;                              // [M][256] bf16
    unsigned short* xb   = scr + (size_t)Mn * 256;           // [M][32]
    unsigned short* w0bf = xb  + (size_t)Mn * 32;            // [2][512][32]
    unsigned short* w1bf = w0bf + 2 * 512 * 32;              // [2][512][256]

    prep<<<2048, 256, 0, stream>>>(x, wih0f, wih0b, wih1f, wih1b, xb, w0bf, w1bf);

    dim3 gg(1024, 8), gb(256);
    dim3 rg(128, 2), rb(256);

    gemm_tile<32, 1><<<gg, gb, 0, stream>>>(xb, 32, w0bf, gx);
    lstm_rec<<<rg, rb, 0, stream>>>(gx, whh0f, whh0b, b0f, b0b, y, y0b, hn, cn, 0);
    gemm_tile<128, 2><<<gg, gb, 0, stream>>>(y0b, 256, w1bf, gx);
    lstm_rec<<<rg, rb, 0, stream>>>(gx, whh1f, whh1b, b1f, b1b, y, y0b, hn, cn, 1);
}